// Round 4
// baseline (459.966 us; speedup 1.0000x reference)
//
#include <hip/hip_runtime.h>
#include <stdint.h>

#define E_ 8
#define M_ 8192
#define K_ 2048
#define N_ 8192

#define BM 256
#define BN 256
#define BK 64
#define NT (K_ / BK)        // 32 K-tiles
#define LDS_BYTES 131072    // 2 dbuf x 64KB

typedef __attribute__((ext_vector_type(8))) short bf16x8;
typedef __attribute__((ext_vector_type(4))) float f32x4;
typedef __attribute__((ext_vector_type(8))) unsigned short us8;

__device__ __forceinline__ unsigned short f2bf(float f) {
  union { float f; uint32_t u; } v; v.f = f;
  uint32_t u = v.u;
  uint32_t r = (u + 0x7FFFu + ((u >> 16) & 1u)) >> 16;
  return (unsigned short)r;
}

__device__ __forceinline__ void gload_lds16(const void* g, void* l) {
  __builtin_amdgcn_global_load_lds(
      (const __attribute__((address_space(1))) unsigned int*)g,
      (__attribute__((address_space(3))) unsigned int*)l,
      16, 0, 0);
}

// ---------------- fp32 -> bf16, layout preserving (inputs) ----------------
__global__ __launch_bounds__(256) void conv_a(const float* __restrict__ A,
                                              unsigned short* __restrict__ Ab,
                                              int n8) {
  int stride = gridDim.x * blockDim.x;
  for (int idx = blockIdx.x * blockDim.x + threadIdx.x; idx < n8; idx += stride) {
    const float4* p = reinterpret_cast<const float4*>(A) + (size_t)idx * 2;
    float4 x0 = p[0], x1 = p[1];
    us8 o;
    o[0] = f2bf(x0.x); o[1] = f2bf(x0.y); o[2] = f2bf(x0.z); o[3] = f2bf(x0.w);
    o[4] = f2bf(x1.x); o[5] = f2bf(x1.y); o[6] = f2bf(x1.z); o[7] = f2bf(x1.w);
    *reinterpret_cast<us8*>(Ab + (size_t)idx * 8) = o;
  }
}

// ------------- fp32 W[e][K][N] -> bf16 Wt[e][N][K] (transpose) -------------
__global__ __launch_bounds__(256) void conv_wT(const float* __restrict__ W,
                                               unsigned short* __restrict__ Wt,
                                               int e_fixed) {
  __shared__ float t[64][65];
  int tid = threadIdx.x;
  int tx = tid & 63, ty = tid >> 6;
  int n0 = blockIdx.x * 64, k0 = blockIdx.y * 64;
  int e = (gridDim.z > 1) ? blockIdx.z : e_fixed;
  size_t win = (size_t)e * K_ * N_;
  size_t wout = (gridDim.z > 1) ? win : 0;

  #pragma unroll
  for (int r = 0; r < 16; ++r) {
    int kl = r * 4 + ty;
    t[kl][tx] = W[win + (size_t)(k0 + kl) * N_ + n0 + tx];
  }
  __syncthreads();
  int px = tid & 31, py = tid >> 5;
  #pragma unroll
  for (int r = 0; r < 8; ++r) {
    int nl = r * 8 + py;
    unsigned int pack = (unsigned int)f2bf(t[2 * px][nl]) |
                        ((unsigned int)f2bf(t[2 * px + 1][nl]) << 16);
    *reinterpret_cast<unsigned int*>(Wt + wout + (size_t)(n0 + nl) * K_ + k0 + 2 * px) = pack;
  }
}

// ------------- grouped bf16 GEMM: 256x256, BK=64, dbuf-2, m201 phase pairs -------------
// LDS dbuf d at d*65536: A @0 (h*16K + ks*8K + row*64 + slot*16), B @32K same.
// slot = kc ^ swz(row), swz(r) = (r&3)^((r>>2)&3)  (2-way residual = free).
// Per K-tile: 4 phases, each {ds_read frag; 2 gload_lds; bar; lgkm0; 16 MFMA; bar},
// vmcnt(4) only at P1/P3 end (counted, never 0 in loop). Stage order ks0-first.
__global__ __launch_bounds__(512, 2) void moe_gemm_bf16(
    const unsigned short* __restrict__ Ab,   // [M][K] bf16
    const unsigned short* __restrict__ Wt,   // [e][N][K] bf16
    const int* __restrict__ gs,
    const float* __restrict__ bias,
    float* __restrict__ C,
    int only_expert, size_t wt_stride) {
  extern __shared__ char smem[];

  int tile_n = blockIdx.x;
  int tile_m = blockIdx.y;

  int expert = -1, row_start = 0, rows = 0;
  if (only_expert >= 0) {
    int off = 0;
    for (int e = 0; e < only_expert; ++e) off += gs[e];
    int g = gs[only_expert];
    int t0 = tile_m * BM;
    if (t0 >= g) return;
    expert = only_expert;
    row_start = off + t0;
    rows = min(BM, g - t0);
  } else {
    int acc = 0, off = 0;
    for (int e = 0; e < E_; ++e) {
      int g = gs[e];
      int t = (g + BM - 1) / BM;
      if (expert < 0 && tile_m < acc + t) {
        int lt = tile_m - acc;
        expert = e;
        row_start = off + lt * BM;
        rows = min(BM, g - lt * BM);
      }
      acc += t;
      off += g;
    }
    if (expert < 0) return;
  }

  const unsigned short* WtE = Wt + (size_t)expert * wt_stride;

  int tid = threadIdx.x;          // 0..511
  int lane = tid & 63;
  int wave = tid >> 6;            // 0..7
  int wr = wave >> 2;             // 0..1 (M half)
  int wc = wave & 3;              // 0..3 (N quarter)
  int bh = wc >> 1;               // B half
  int ln15 = lane & 15;
  int n0 = tile_n * BN;

  // ---- fragment read bases (swizzled) ----
  int sl16 = (((lane >> 4) ^ ((ln15 & 3) ^ ((ln15 >> 2) & 3))) << 4);
  int aRB = wr * 16384 + ln15 * 64 + sl16;                           // +mi*1024 +ks*8192
  int bRB = 32768 + bh * 16384 + ((wc & 1) * 64 + ln15) * 64 + sl16; // +nj*1024 +ks*8192

  // ---- staging precompute: thread stages 16B of each 8KB (X,h,ks) chunk ----
  int soff = tid * 16;
  int srow = soff >> 6;           // 0..127
  int sslot = (soff >> 4) & 3;
  int skc = sslot ^ ((srow & 3) ^ ((srow >> 2) & 3));
  int scol0 = skc * 8;

  const unsigned short* aS[2][2];  // [h][ks]
  const unsigned short* bS[2][2];
  #pragma unroll
  for (int h = 0; h < 2; ++h) {
    int r = h * 128 + srow;
    int gr = r < rows ? r : 0;     // clamp partial M tiles
    #pragma unroll
    for (int ks = 0; ks < 2; ++ks) {
      aS[h][ks] = Ab + (size_t)(row_start + gr) * K_ + ks * 32 + scol0;
      bS[h][ks] = WtE + (size_t)(n0 + h * 128 + srow) * K_ + ks * 32 + scol0;
    }
  }

#define STG_A(DB, h, ks, kt) \
  gload_lds16(aS[h][ks] + (kt) * 64, smem + (DB) + (h) * 16384 + (ks) * 8192 + soff)
#define STG_B(DB, h, ks, kt) \
  gload_lds16(bS[h][ks] + (kt) * 64, smem + (DB) + 32768 + (h) * 16384 + (ks) * 8192 + soff)

  f32x4 acc4[8][4];
  #pragma unroll
  for (int i = 0; i < 8; ++i)
    #pragma unroll
    for (int j = 0; j < 4; ++j)
      acc4[i][j] = f32x4{0.f, 0.f, 0.f, 0.f};

#define DS_A(frag, DB, KS, MIBASE)                                            \
  _Pragma("unroll") for (int mi = 0; mi < 4; ++mi)                            \
    frag[mi] = *(const bf16x8*)(smem + (DB) + aRB + (KS) * 8192 +             \
                                ((MIBASE) + mi) * 1024);
#define DS_B(frag, DB, KS)                                                    \
  _Pragma("unroll") for (int nj = 0; nj < 4; ++nj)                            \
    frag[nj] = *(const bf16x8*)(smem + (DB) + bRB + (KS) * 8192 + nj * 1024);
#define MFMA16(MB, af, bf)                                                    \
  __builtin_amdgcn_s_setprio(1);                                              \
  _Pragma("unroll") for (int mi = 0; mi < 4; ++mi)                            \
    _Pragma("unroll") for (int nj = 0; nj < 4; ++nj)                          \
      acc4[(MB) + mi][nj] = __builtin_amdgcn_mfma_f32_16x16x32_bf16(          \
          af[mi], bf[nj], acc4[(MB) + mi][nj], 0, 0, 0);                      \
  __builtin_amdgcn_s_setprio(0);

  // Per-phase: {ds_read ; 2 stages ; s_barrier ; lgkmcnt(0) ; 16 MFMA ; s_barrier}
#define TILE4(DB, DBN, KTN)                                                   \
  do {                                                                        \
    bf16x8 af[4], bf[4];                                                      \
    /* P0: ks0, m-half 0 (+B ks0) */                                          \
    DS_A(af, DB, 0, 0); DS_B(bf, DB, 0);                                      \
    STG_A(DBN, 0, 0, KTN); STG_B(DBN, 0, 0, KTN);                             \
    __builtin_amdgcn_s_barrier();                                             \
    asm volatile("s_waitcnt lgkmcnt(0)" ::: "memory");                        \
    __builtin_amdgcn_sched_barrier(0);                                        \
    MFMA16(0, af, bf);                                                        \
    __builtin_amdgcn_s_barrier();                                             \
    /* P1: ks0, m-half 1 (B reused in regs) */                                \
    DS_A(af, DB, 0, 4);                                                       \
    STG_A(DBN, 1, 0, KTN); STG_B(DBN, 1, 0, KTN);                             \
    __builtin_amdgcn_s_barrier();                                             \
    asm volatile("s_waitcnt lgkmcnt(0)" ::: "memory");                        \
    __builtin_amdgcn_sched_barrier(0);                                        \
    MFMA16(4, af, bf);                                                        \
    asm volatile("s_waitcnt vmcnt(4)" ::: "memory");                          \
    __builtin_amdgcn_s_barrier();                                             \
    /* P2: ks1, m-half 0 (+B ks1) */                                          \
    DS_A(af, DB, 1, 0); DS_B(bf, DB, 1);                                      \
    STG_A(DBN, 0, 1, KTN); STG_B(DBN, 0, 1, KTN);                             \
    __builtin_amdgcn_s_barrier();                                             \
    asm volatile("s_waitcnt lgkmcnt(0)" ::: "memory");                        \
    __builtin_amdgcn_sched_barrier(0);                                        \
    MFMA16(0, af, bf);                                                        \
    __builtin_amdgcn_s_barrier();                                             \
    /* P3: ks1, m-half 1 */                                                   \
    DS_A(af, DB, 1, 4);                                                       \
    STG_A(DBN, 1, 1, KTN); STG_B(DBN, 1, 1, KTN);                             \
    __builtin_amdgcn_s_barrier();                                             \
    asm volatile("s_waitcnt lgkmcnt(0)" ::: "memory");                        \
    __builtin_amdgcn_sched_barrier(0);                                        \
    MFMA16(4, af, bf);                                                        \
    asm volatile("s_waitcnt vmcnt(4)" ::: "memory");                          \
    __builtin_amdgcn_s_barrier();                                             \
  } while (0)

  // prologue: stage tile 0 into dbuf0, ks0 chunks first (vmcnt counting order)
  STG_A(0, 0, 0, 0); STG_B(0, 0, 0, 0);
  STG_A(0, 1, 0, 0); STG_B(0, 1, 0, 0);
  STG_A(0, 0, 1, 0); STG_B(0, 0, 1, 0);
  STG_A(0, 1, 1, 0); STG_B(0, 1, 1, 0);
  asm volatile("s_waitcnt vmcnt(4)" ::: "memory");  // tile0 ks0 landed
  __builtin_amdgcn_s_barrier();

  for (int t2 = 0; t2 < NT; t2 += 2) {
    int ktn2 = (t2 + 2 >= NT) ? 0 : t2 + 2;  // wrap: dead stores, uniform counts
    TILE4(0, 65536, t2 + 1);
    TILE4(65536, 0, ktn2);
  }
#undef TILE4
#undef DS_A
#undef DS_B
#undef MFMA16
#undef STG_A
#undef STG_B

  asm volatile("s_waitcnt vmcnt(0)" ::: "memory");  // drain wrapped tail stages

  // epilogue: C = acc + bias ; C/D layout col=lane&15, row=(lane>>4)*4+reg
  float bv[4];
  #pragma unroll
  for (int nj = 0; nj < 4; ++nj) bv[nj] = bias[n0 + wc * 64 + nj * 16 + ln15];
  #pragma unroll
  for (int mi = 0; mi < 8; ++mi) {
    int r0 = wr * 128 + mi * 16 + (lane >> 4) * 4;
    #pragma unroll
    for (int r = 0; r < 4; ++r) {
      int lr = r0 + r;
      if (lr < rows) {
        float* Cp = C + (size_t)(row_start + lr) * N_ + n0 + wc * 64 + ln15;
        #pragma unroll
        for (int nj = 0; nj < 4; ++nj) Cp[nj * 16] = acc4[mi][nj][r] + bv[nj];
      }
    }
  }
}

// ---------------- naive fp32 fallback (only if workspace too small) ----------------
__global__ __launch_bounds__(256) void moe_naive(const float* __restrict__ A,
                                                 const float* __restrict__ W,
                                                 const int* __restrict__ gs,
                                                 const float* __restrict__ bias,
                                                 float* __restrict__ C) {
  int col = blockIdx.x * 16 + (threadIdx.x & 15);
  int row = blockIdx.y * 16 + (threadIdx.x >> 4);
  int acc = 0, e = E_ - 1;
  for (int i = 0; i < E_; ++i) {
    int g = gs[i];
    if (row >= acc && row < acc + g) { e = i; break; }
    acc += g;
  }
  const float* a = A + (size_t)row * K_;
  const float* w = W + (size_t)e * K_ * N_ + col;
  float s = 0.f;
  for (int k = 0; k < K_; ++k) s += a[k] * w[(size_t)k * N_];
  C[(size_t)row * N_ + col] = s + bias[col];
}

extern "C" void kernel_launch(void* const* d_in, const int* in_sizes, int n_in,
                              void* d_out, int out_size, void* d_ws, size_t ws_size,
                              hipStream_t stream) {
  const float* A = (const float*)d_in[0];
  const float* W = (const float*)d_in[1];
  const int* gs = (const int*)d_in[2];
  const float* bias = (const float*)d_in[3];
  float* C = (float*)d_out;

  const size_t needA = (size_t)M_ * K_ * 2;          // 32 MiB
  const size_t needWall = (size_t)E_ * K_ * N_ * 2;  // 256 MiB
  const size_t needW1 = (size_t)K_ * N_ * 2;         // 32 MiB

  (void)hipFuncSetAttribute((const void*)moe_gemm_bf16,
                            hipFuncAttributeMaxDynamicSharedMemorySize, LDS_BYTES);

  if (ws_size >= needA + needWall) {
    unsigned short* Abf = (unsigned short*)d_ws;
    unsigned short* Wtb = (unsigned short*)((char*)d_ws + needA);
    conv_a<<<2048, 256, 0, stream>>>(A, Abf, (M_ * K_) / 8);
    dim3 gw(N_ / 64, K_ / 64, E_);
    conv_wT<<<gw, 256, 0, stream>>>(W, Wtb, 0);
    dim3 gg(N_ / BN, M_ / BM + E_);
    moe_gemm_bf16<<<gg, 512, LDS_BYTES, stream>>>(Abf, Wtb, gs, bias, C, -1, (size_t)N_ * K_);
  } else if (ws_size >= needA + needW1) {
    unsigned short* Abf = (unsigned short*)d_ws;
    unsigned short* Wtb = (unsigned short*)((char*)d_ws + needA);
    conv_a<<<2048, 256, 0, stream>>>(A, Abf, (M_ * K_) / 8);
    for (int e = 0; e < E_; ++e) {
      dim3 gw(N_ / 64, K_ / 64, 1);
      conv_wT<<<gw, 256, 0, stream>>>(W, Wtb, e);
      dim3 gg(N_ / BN, M_ / BM);
      moe_gemm_bf16<<<gg, 512, LDS_BYTES, stream>>>(Abf, Wtb, gs, bias, C, e, 0);
    }
  } else {
    dim3 gn(N_ / 16, M_ / 16);
    moe_naive<<<gn, 256, 0, stream>>>(A, W, gs, bias, C);
  }
}

// Round 5
// 428.296 us; speedup vs baseline: 1.0739x; 1.0739x over previous
//
#include <hip/hip_runtime.h>
#include <stdint.h>

#define E_ 8
#define M_ 8192
#define K_ 2048
#define N_ 8192

#define BM 256
#define BN 256
#define BK 64
#define NT (K_ / BK)        // 32 K-tiles
#define LDS_BYTES 131072    // 2 dbuf x 64KB

typedef __attribute__((ext_vector_type(8))) short bf16x8;
typedef __attribute__((ext_vector_type(4))) float f32x4;
typedef __attribute__((ext_vector_type(8))) unsigned short us8;

__device__ __forceinline__ unsigned short f2bf(float f) {
  union { float f; uint32_t u; } v; v.f = f;
  uint32_t u = v.u;
  uint32_t r = (u + 0x7FFFu + ((u >> 16) & 1u)) >> 16;
  return (unsigned short)r;
}

__device__ __forceinline__ void gload_lds16(const void* g, void* l) {
  __builtin_amdgcn_global_load_lds(
      (const __attribute__((address_space(1))) unsigned int*)g,
      (__attribute__((address_space(3))) unsigned int*)l,
      16, 0, 0);
}

// ---------------- fp32 -> bf16, layout preserving (inputs) ----------------
__global__ __launch_bounds__(256) void conv_a(const float* __restrict__ A,
                                              unsigned short* __restrict__ Ab,
                                              int n8) {
  int stride = gridDim.x * blockDim.x;
  for (int idx = blockIdx.x * blockDim.x + threadIdx.x; idx < n8; idx += stride) {
    const float4* p = reinterpret_cast<const float4*>(A) + (size_t)idx * 2;
    float4 x0 = p[0], x1 = p[1];
    us8 o;
    o[0] = f2bf(x0.x); o[1] = f2bf(x0.y); o[2] = f2bf(x0.z); o[3] = f2bf(x0.w);
    o[4] = f2bf(x1.x); o[5] = f2bf(x1.y); o[6] = f2bf(x1.z); o[7] = f2bf(x1.w);
    *reinterpret_cast<us8*>(Ab + (size_t)idx * 8) = o;
  }
}

// ------------- fp32 W[e][K][N] -> bf16 Wt[e][N][K] (transpose) -------------
__global__ __launch_bounds__(256) void conv_wT(const float* __restrict__ W,
                                               unsigned short* __restrict__ Wt,
                                               int e_fixed) {
  __shared__ float t[64][65];
  int tid = threadIdx.x;
  int tx = tid & 63, ty = tid >> 6;
  int n0 = blockIdx.x * 64, k0 = blockIdx.y * 64;
  int e = (gridDim.z > 1) ? blockIdx.z : e_fixed;
  size_t win = (size_t)e * K_ * N_;
  size_t wout = (gridDim.z > 1) ? win : 0;

  #pragma unroll
  for (int r = 0; r < 16; ++r) {
    int kl = r * 4 + ty;
    t[kl][tx] = W[win + (size_t)(k0 + kl) * N_ + n0 + tx];
  }
  __syncthreads();
  int px = tid & 31, py = tid >> 5;
  #pragma unroll
  for (int r = 0; r < 8; ++r) {
    int nl = r * 8 + py;
    unsigned int pack = (unsigned int)f2bf(t[2 * px][nl]) |
                        ((unsigned int)f2bf(t[2 * px + 1][nl]) << 16);
    *reinterpret_cast<unsigned int*>(Wt + wout + (size_t)(n0 + nl) * K_ + k0 + 2 * px) = pack;
  }
}

// ------- grouped bf16 GEMM: 256x256, BK=64, dbuf-2, 4-phase, r2 swizzle -------
// LDS dbuf d at d*65536: A @0 (256 rows x 128B), B @32768 (256 rows x 128B).
// Row r: 8 slots of 16B; k-quarter q stored at phys slot q ^ (r&7)  (r2 layout,
// measured 0 bank conflicts). Stage chunk = 64 rows = 8KB (block-wide).
// Per K-tile: 4 phases {ds_read; 2 chunk stages; bar; lgkm0; 16 MFMA; bar},
// vmcnt(2) at end of P0 and P3 only - counted, never 0 in loop.
__global__ __launch_bounds__(512, 2) void moe_gemm_bf16(
    const unsigned short* __restrict__ Ab,   // [M][K] bf16
    const unsigned short* __restrict__ Wt,   // [e][N][K] bf16
    const int* __restrict__ gs,
    const float* __restrict__ bias,
    float* __restrict__ C,
    int only_expert, size_t wt_stride) {
  extern __shared__ char smem[];

  int tile_n = blockIdx.x;
  int tile_m = blockIdx.y;

  int expert = -1, row_start = 0, rows = 0;
  if (only_expert >= 0) {
    int off = 0;
    for (int e = 0; e < only_expert; ++e) off += gs[e];
    int g = gs[only_expert];
    int t0 = tile_m * BM;
    if (t0 >= g) return;
    expert = only_expert;
    row_start = off + t0;
    rows = min(BM, g - t0);
  } else {
    int acc = 0, off = 0;
    for (int e = 0; e < E_; ++e) {
      int g = gs[e];
      int t = (g + BM - 1) / BM;
      if (expert < 0 && tile_m < acc + t) {
        int lt = tile_m - acc;
        expert = e;
        row_start = off + lt * BM;
        rows = min(BM, g - lt * BM);
      }
      acc += t;
      off += g;
    }
    if (expert < 0) return;
  }

  const unsigned short* WtE = Wt + (size_t)expert * wt_stride;

  int tid = threadIdx.x;          // 0..511
  int lane = tid & 63;
  int wave = tid >> 6;            // 0..7
  int wr = wave >> 2;             // 0..1 (M half)
  int wc = wave & 3;              // 0..3 (N quarter)
  int bh = wc >> 1;               // B 128-half
  int ln15 = lane & 15;
  int n0 = tile_n * BN;

  // ---- fragment read bases (r2 swizzle: phys slot = logical ^ (row&7)) ----
  int slot0 = (((lane >> 4) ^ (ln15 & 7)) << 4);   // ks0 byte off in row; ks1 = ^64
  int aBase = wr * 16384 + ln15 * 128;             // + mh*8192 + mi*2048
  int bBase = 32768 + bh * 16384 + (wc & 1) * 8192 + ln15 * 128;  // + nj*2048

  // ---- staging precompute: thread stages 16B of each 8KB (64-row) chunk ----
  int soff = tid * 16;            // dest byte within chunk (= crow*128 + p*16)
  int crow = tid >> 3;            // 0..63
  int lslot = (tid & 7) ^ (crow & 7);
  int scol = lslot * 8;           // bf16 col within 64 (+kt*64 per tile)

  const unsigned short* aS[4];
  const unsigned short* bS[4];
  #pragma unroll
  for (int c = 0; c < 4; ++c) {
    int r = c * 64 + crow;
    int gr = r < rows ? r : 0;     // clamp partial M tiles
    aS[c] = Ab + (size_t)(row_start + gr) * K_ + scol;
    bS[c] = WtE + (size_t)(n0 + r) * K_ + scol;
  }

#define STG_A(DB, c, kt) \
  gload_lds16(aS[c] + (kt) * 64, smem + (DB) + (c) * 8192 + soff)
#define STG_B(DB, c, kt) \
  gload_lds16(bS[c] + (kt) * 64, smem + (DB) + 32768 + (c) * 8192 + soff)

  f32x4 acc4[8][4];
  #pragma unroll
  for (int i = 0; i < 8; ++i)
    #pragma unroll
    for (int j = 0; j < 4; ++j)
      acc4[i][j] = f32x4{0.f, 0.f, 0.f, 0.f};

#define DS_A(frag, DB, MH, KS)                                                \
  _Pragma("unroll") for (int mi = 0; mi < 4; ++mi)                            \
    frag[mi] = *(const bf16x8*)(smem + (DB) + aBase + (MH) * 8192 +           \
                                mi * 2048 + (slot0 ^ ((KS) << 6)));
#define DS_B(frag, DB, KS)                                                    \
  _Pragma("unroll") for (int nj = 0; nj < 4; ++nj)                            \
    frag[nj] = *(const bf16x8*)(smem + (DB) + bBase + nj * 2048 +             \
                                (slot0 ^ ((KS) << 6)));
#define MFMA16(MB, af, bf)                                                    \
  __builtin_amdgcn_s_setprio(1);                                              \
  _Pragma("unroll") for (int mi = 0; mi < 4; ++mi)                            \
    _Pragma("unroll") for (int nj = 0; nj < 4; ++nj)                          \
      acc4[(MB) + mi][nj] = __builtin_amdgcn_mfma_f32_16x16x32_bf16(          \
          af[mi], bf[nj], acc4[(MB) + mi][nj], 0, 0, 0);                      \
  __builtin_amdgcn_s_setprio(0);

  // Per K-tile: P0 (ks0,mh0 +B), P1 (ks0,mh1), P2 (ks1,mh0 +B), P3 (ks1,mh1).
  // Stage next tile in consumption order: B0,B1 | B2,B3 | A0,A2 | A1,A3.
#define TILE4(DB, DBN, KTN)                                                   \
  do {                                                                        \
    bf16x8 af[4], bf[4];                                                      \
    /* P0 */                                                                  \
    DS_A(af, DB, 0, 0); DS_B(bf, DB, 0);                                      \
    STG_B(DBN, 0, KTN); STG_B(DBN, 1, KTN);                                   \
    __builtin_amdgcn_s_barrier();                                             \
    asm volatile("s_waitcnt lgkmcnt(0)" ::: "memory");                        \
    __builtin_amdgcn_sched_barrier(0);                                        \
    MFMA16(0, af, bf);                                                        \
    asm volatile("s_waitcnt vmcnt(2)" ::: "memory");                          \
    __builtin_amdgcn_s_barrier();                                             \
    /* P1 (B reused in regs) */                                               \
    DS_A(af, DB, 1, 0);                                                       \
    STG_B(DBN, 2, KTN); STG_B(DBN, 3, KTN);                                   \
    __builtin_amdgcn_s_barrier();                                             \
    asm volatile("s_waitcnt lgkmcnt(0)" ::: "memory");                        \
    __builtin_amdgcn_sched_barrier(0);                                        \
    MFMA16(4, af, bf);                                                        \
    __builtin_amdgcn_s_barrier();                                             \
    /* P2 */                                                                  \
    DS_A(af, DB, 0, 1); DS_B(bf, DB, 1);                                      \
    STG_A(DBN, 0, KTN); STG_A(DBN, 2, KTN);                                   \
    __builtin_amdgcn_s_barrier();                                             \
    asm volatile("s_waitcnt lgkmcnt(0)" ::: "memory");                        \
    __builtin_amdgcn_sched_barrier(0);                                        \
    MFMA16(0, af, bf);                                                        \
    __builtin_amdgcn_s_barrier();                                             \
    /* P3 */                                                                  \
    DS_A(af, DB, 1, 1);                                                       \
    STG_A(DBN, 1, KTN); STG_A(DBN, 3, KTN);                                   \
    __builtin_amdgcn_s_barrier();                                             \
    asm volatile("s_waitcnt lgkmcnt(0)" ::: "memory");                        \
    __builtin_amdgcn_sched_barrier(0);                                        \
    MFMA16(4, af, bf);                                                        \
    asm volatile("s_waitcnt vmcnt(2)" ::: "memory");                          \
    __builtin_amdgcn_s_barrier();                                             \
  } while (0)

  // prologue: stage tile 0 into dbuf0 in consumption order
  STG_B(0, 0, 0); STG_B(0, 1, 0); STG_B(0, 2, 0); STG_B(0, 3, 0);
  STG_A(0, 0, 0); STG_A(0, 2, 0);
  STG_A(0, 1, 0); STG_A(0, 3, 0);
  asm volatile("s_waitcnt vmcnt(2)" ::: "memory");  // first 6 chunks landed
  __builtin_amdgcn_s_barrier();

  for (int t2 = 0; t2 < NT; t2 += 2) {
    int k2 = (t2 + 2 >= NT) ? 0 : t2 + 2;  // wrap: dead stores, uniform counts
    TILE4(0, 65536, t2 + 1);
    TILE4(65536, 0, k2);
  }
#undef TILE4
#undef DS_A
#undef DS_B
#undef MFMA16
#undef STG_A
#undef STG_B

  asm volatile("s_waitcnt vmcnt(0)" ::: "memory");  // drain wrapped tail stages

  // epilogue: C = acc + bias ; C/D layout col=lane&15, row=(lane>>4)*4+reg
  float bv[4];
  #pragma unroll
  for (int nj = 0; nj < 4; ++nj) bv[nj] = bias[n0 + wc * 64 + nj * 16 + ln15];
  #pragma unroll
  for (int mi = 0; mi < 8; ++mi) {
    int r0 = wr * 128 + mi * 16 + (lane >> 4) * 4;
    #pragma unroll
    for (int r = 0; r < 4; ++r) {
      int lr = r0 + r;
      if (lr < rows) {
        float* Cp = C + (size_t)(row_start + lr) * N_ + n0 + wc * 64 + ln15;
        #pragma unroll
        for (int nj = 0; nj < 4; ++nj) Cp[nj * 16] = acc4[mi][nj][r] + bv[nj];
      }
    }
  }
}

// ---------------- naive fp32 fallback (only if workspace too small) ----------------
__global__ __launch_bounds__(256) void moe_naive(const float* __restrict__ A,
                                                 const float* __restrict__ W,
                                                 const int* __restrict__ gs,
                                                 const float* __restrict__ bias,
                                                 float* __restrict__ C) {
  int col = blockIdx.x * 16 + (threadIdx.x & 15);
  int row = blockIdx.y * 16 + (threadIdx.x >> 4);
  int acc = 0, e = E_ - 1;
  for (int i = 0; i < E_; ++i) {
    int g = gs[i];
    if (row >= acc && row < acc + g) { e = i; break; }
    acc += g;
  }
  const float* a = A + (size_t)row * K_;
  const float* w = W + (size_t)e * K_ * N_ + col;
  float s = 0.f;
  for (int k = 0; k < K_; ++k) s += a[k] * w[(size_t)k * N_];
  C[(size_t)row * N_ + col] = s + bias[col];
}

extern "C" void kernel_launch(void* const* d_in, const int* in_sizes, int n_in,
                              void* d_out, int out_size, void* d_ws, size_t ws_size,
                              hipStream_t stream) {
  const float* A = (const float*)d_in[0];
  const float* W = (const float*)d_in[1];
  const int* gs = (const int*)d_in[2];
  const float* bias = (const float*)d_in[3];
  float* C = (float*)d_out;

  const size_t needA = (size_t)M_ * K_ * 2;          // 32 MiB
  const size_t needWall = (size_t)E_ * K_ * N_ * 2;  // 256 MiB
  const size_t needW1 = (size_t)K_ * N_ * 2;         // 32 MiB

  (void)hipFuncSetAttribute((const void*)moe_gemm_bf16,
                            hipFuncAttributeMaxDynamicSharedMemorySize, LDS_BYTES);

  if (ws_size >= needA + needWall) {
    unsigned short* Abf = (unsigned short*)d_ws;
    unsigned short* Wtb = (unsigned short*)((char*)d_ws + needA);
    conv_a<<<2048, 256, 0, stream>>>(A, Abf, (M_ * K_) / 8);
    dim3 gw(N_ / 64, K_ / 64, E_);
    conv_wT<<<gw, 256, 0, stream>>>(W, Wtb, 0);
    dim3 gg(N_ / BN, M_ / BM + E_);
    moe_gemm_bf16<<<gg, 512, LDS_BYTES, stream>>>(Abf, Wtb, gs, bias, C, -1, (size_t)N_ * K_);
  } else if (ws_size >= needA + needW1) {
    unsigned short* Abf = (unsigned short*)d_ws;
    unsigned short* Wtb = (unsigned short*)((char*)d_ws + needA);
    conv_a<<<2048, 256, 0, stream>>>(A, Abf, (M_ * K_) / 8);
    for (int e = 0; e < E_; ++e) {
      dim3 gw(N_ / 64, K_ / 64, 1);
      conv_wT<<<gw, 256, 0, stream>>>(W, Wtb, e);
      dim3 gg(N_ / BN, M_ / BM);
      moe_gemm_bf16<<<gg, 512, LDS_BYTES, stream>>>(Abf, Wtb, gs, bias, C, e, 0);
    }
  } else {
    dim3 gn(N_ / 16, M_ / 16);
    moe_naive<<<gn, 256, 0, stream>>>(A, W, gs, bias, C);
  }
}